// Round 7
// baseline (246.768 us; speedup 1.0000x reference)
//
#include <hip/hip_runtime.h>

// FastAttention (Performer-style, causal) on MI355X — single fused kernel.
// B=2, S=1024, H=8, DEPTH=64, NFEAT=64, D_MODEL=512. fp32 in/out, bf16 MFMA inside.
//
// One kernel, grid 256 x 512, hand-rolled grid barrier (device-scope atomics).
// Phases: P0 weights (blocks 0-15; all blocks preload inputs) | P1 proj+feature+
// chunk-sums (per-tile, all through LDS) | P2 chunk prefix (global CST/KCS) |
// P3 causal attention (LDS-resident phi/v) | P4 output FC.
// Only CST/KCS (cross-block prefix) and O (re-tiled by FC) touch global between phases.

#define SS 1024
#define HH 8
#define DD 64
#define FF 64
#define DM 512
#define NCH 16

typedef __bf16 bf16_t;
typedef __attribute__((ext_vector_type(8))) __bf16 bf16x8;
typedef __attribute__((ext_vector_type(4))) __bf16 bf16x4;
typedef __attribute__((ext_vector_type(4))) float f32x4;

#define MFMA16(a,b,c) __builtin_amdgcn_mfma_f32_16x16x32_bf16((a),(b),(c),0,0,0)

__device__ inline bf16x8 pack8(float4 x, float4 y){
    bf16x8 r;
    r[0]=(__bf16)x.x; r[1]=(__bf16)x.y; r[2]=(__bf16)x.z; r[3]=(__bf16)x.w;
    r[4]=(__bf16)y.x; r[5]=(__bf16)y.y; r[6]=(__bf16)y.z; r[7]=(__bf16)y.w;
    return r;
}
__device__ inline bf16x8 cvt_f32x8(const float* p){
    const float4* p4 = (const float4*)p;
    return pack8(p4[0], p4[1]);
}

// grid barrier: all 256 blocks arrive at slot, then proceed.
__device__ inline void gsync(unsigned* cnt, int slot){
    __syncthreads();   // drains this block's vmem (compiler emits vmcnt(0) before s_barrier)
    if (threadIdx.x == 0){
        __threadfence();   // release: write-back L2 (device scope)
        __hip_atomic_fetch_add(cnt + slot, 1u, __ATOMIC_ACQ_REL, __HIP_MEMORY_SCOPE_AGENT);
        while (__hip_atomic_load(cnt + slot, __ATOMIC_ACQUIRE, __HIP_MEMORY_SCOPE_AGENT) < 256u)
            __builtin_amdgcn_s_sleep(2);
        __threadfence();   // acquire: invalidate L1/L2 so cross-XCD writes are visible
    }
    __syncthreads();
}

__global__ __launch_bounds__(512, 2) void kfused(
    const float* __restrict__ q_in, const float* __restrict__ k_in,
    const float* __restrict__ v_in,
    const float* __restrict__ Wq, const float* __restrict__ bq,
    const float* __restrict__ Wk, const float* __restrict__ bk,
    const float* __restrict__ Wv, const float* __restrict__ bv,
    const float* __restrict__ orf_q, const float* __restrict__ orf_k,
    const float* __restrict__ Wfc, const float* __restrict__ bfc,
    bf16_t* __restrict__ Mtq, bf16_t* __restrict__ Mtk,
    float* __restrict__ cq, float* __restrict__ ck,
    bf16_t* __restrict__ WvB, bf16_t* __restrict__ WfcB,
    float* __restrict__ CST, float* __restrict__ KCS,
    bf16_t* __restrict__ O, unsigned* __restrict__ syncc,
    float* __restrict__ out)
{
    // LDS overlay (64512 B total):
    //  [0,17408)      dsT [64][68] f32 (P1)   / kct [64][67] f32 (P3)
    //  [17408,26624)  kt  [64][72] bf16 (P1->P3 S1) / sAl [64][72] bf16 (P3 S4+)
    //  [26624,35840)  vt  [64][72] bf16 (persists P1 -> P3 S5)
    //  [35840,45056)  qnl [64][72] bf16 (P3)
    //  [45056,54272)  phql[64][72] bf16 (P1 -> P3)
    //  [54272,63488)  phkl[64][72] bf16 (P1 -> P3)
    //  [63488,64512)  part/scanp [256] f32
    __shared__ __align__(16) char smem[64512];
    float*  dsT  = (float*)smem;
    float*  kct  = (float*)smem;
    bf16_t* kt   = (bf16_t*)(smem + 17408);
    bf16_t* sAl  = (bf16_t*)(smem + 17408);
    bf16_t* vt   = (bf16_t*)(smem + 26624);
    bf16_t* qnl  = (bf16_t*)(smem + 35840);
    bf16_t* phql = (bf16_t*)(smem + 45056);
    bf16_t* phkl = (bf16_t*)(smem + 54272);
    float*  part = (float*)(smem + 63488);

    const int tid = threadIdx.x;
    const int l = tid & 63;
    const int w = __builtin_amdgcn_readfirstlane(tid >> 6);  // 0..7
    const int ww = w & 3;
    const int qd = l >> 4, m = l & 15;
    const int bid = blockIdx.x;
    const int bh = bid >> 4, ch = bid & 15;
    const int b = bh >> 3, h = bh & 7;
    const int s0 = ch*64;
    const int sw = s0 + ww*16;

    // ---- P0a: preload this block's input rows (overlaps weight phase) ----
    const float* xrow = ((w < 4) ? q_in : k_in) + ((size_t)(b*SS + sw + m))*DM + h*DD;
    float4 pA0 = *(const float4*)(xrow + qd*8);
    float4 pA1 = *(const float4*)(xrow + qd*8 + 4);
    float4 pB0 = *(const float4*)(xrow + 32 + qd*8);
    float4 pB1 = *(const float4*)(xrow + 32 + qd*8 + 4);
    float4 vA0 = {0,0,0,0}, vA1 = {0,0,0,0}, vB0 = {0,0,0,0}, vB1 = {0,0,0,0};
    if (w >= 4){
        const float* vrow = v_in + ((size_t)(b*SS + sw + m))*DM + h*DD;
        vA0 = *(const float4*)(vrow + qd*8);
        vA1 = *(const float4*)(vrow + qd*8 + 4);
        vB0 = *(const float4*)(vrow + 32 + qd*8);
        vB1 = *(const float4*)(vrow + 32 + qd*8 + 4);
    }

    // ---- P0b: weight prep (blocks 0-15) ----
    if (bid < 2){
        if (tid < 256){
            const float* ORF = bid ? orf_k : orf_q;
            const float* W   = bid ? Wk : Wq;
            const float* bb  = bid ? bk : bq;
            bf16_t* Mt = bid ? Mtk : Mtq;
            float* cc  = bid ? ck : cq;
            const float norm = 0.35355339059327373f; // 64^-0.25
            const int f = tid >> 2, d0 = (tid & 3) * 16;
            float acc[16];
            #pragma unroll
            for (int j=0;j<16;j++) acc[j]=0.f;
            float bacc = 0.f;
            for (int e=0;e<64;e++){
                float oe = ORF[f*64+e];
                const float* wr = W + e*64 + d0;
                #pragma unroll
                for (int j=0;j<16;j++) acc[j] += oe*wr[j];
                bacc += oe*bb[e];
            }
            #pragma unroll
            for (int j=0;j<16;j++) Mt[f*64+d0+j] = (__bf16)(norm*acc[j]);
            if ((tid&3)==0) cc[f] = norm*bacc;
        }
    } else if (bid == 2){
        for (int i=tid;i<4096;i+=512) WvB[i] = (__bf16)Wv[i];
    } else if (bid < 16){
        const float4* W4 = (const float4*)Wfc;
        for (int i=(bid-3)*512+tid; i<65536; i+=13*512){
            float4 v = W4[i];
            bf16x4 o; o[0]=(__bf16)v.x; o[1]=(__bf16)v.y; o[2]=(__bf16)v.z; o[3]=(__bf16)v.w;
            *(bf16x4*)(WfcB + 4*i) = o;
        }
    }
    gsync(syncc, 0);

    // ================= P1: projection + feature map + chunk sums =================
    {
        bf16x8 a0 = pack8(pA0, pA1);
        bf16x8 a1 = pack8(pB0, pB1);
        if (w < 4){
            // q-proj -> phql [s][f]
            #pragma unroll
            for (int nt=0;nt<4;nt++){
                const int f = nt*16 + m;
                float cb = cq[f];
                f32x4 acc = {cb,cb,cb,cb};
                acc = MFMA16(a0, *(const bf16x8*)(Mtq + f*64 + qd*8), acc);
                acc = MFMA16(a1, *(const bf16x8*)(Mtq + f*64 + 32 + qd*8), acc);
                #pragma unroll
                for (int r=0;r<4;r++){
                    float v = acc[r];
                    v = (v>0.f)?v:0.f; v += 0.001f;
                    phql[(ww*16 + qd*4 + r)*72 + f] = (__bf16)v;
                }
            }
        } else {
            // k-proj -> kt [f][s] + phkl [t][f]
            #pragma unroll
            for (int nt=0;nt<4;nt++){
                const int f = nt*16 + m;
                float cb = ck[f];
                f32x4 acc = {cb,cb,cb,cb};
                acc = MFMA16(a0, *(const bf16x8*)(Mtk + f*64 + qd*8), acc);
                acc = MFMA16(a1, *(const bf16x8*)(Mtk + f*64 + 32 + qd*8), acc);
                #pragma unroll
                for (int r=0;r<4;r++){
                    float v = acc[r];
                    v = (v>0.f)?v:0.f; v += 0.001f;
                    __bf16 h16 = (__bf16)v;
                    kt[f*72 + ww*16 + qd*4 + r] = h16;
                    phkl[(ww*16 + qd*4 + r)*72 + f] = h16;
                }
            }
        }
    }
    __syncthreads();
    // v-proj (waves 4-7) -> vt [d][s]
    if (w >= 4){
        bf16x8 va0 = pack8(vA0, vA1);
        bf16x8 va1 = pack8(vB0, vB1);
        #pragma unroll
        for (int nt=0;nt<4;nt++){
            const int e = nt*16 + m;
            float cb = bv[e];
            f32x4 acc = {cb,cb,cb,cb};
            acc = MFMA16(va0, *(const bf16x8*)(WvB + e*64 + qd*8), acc);
            acc = MFMA16(va1, *(const bf16x8*)(WvB + e*64 + 32 + qd*8), acc);
            #pragma unroll
            for (int r=0;r<4;r++)
                vt[e*72 + ww*16 + qd*4 + r] = (__bf16)acc[r];
        }
    }
    __syncthreads();
    // chunk-sum MFMA (all 8 waves) + phi_k column sums (waves 4-7)
    {
        const int ft = ww, np = (w >> 2) * 2;
        bf16x8 a0 = *(bf16x8*)&kt[(ft*16+m)*72 + qd*8];
        bf16x8 a1 = *(bf16x8*)&kt[(ft*16+m)*72 + 32 + qd*8];
        #pragma unroll
        for (int j=0;j<2;j++){
            const int nt = np + j;
            f32x4 acc = {0.f,0.f,0.f,0.f};
            acc = MFMA16(a0, *(bf16x8*)&vt[(nt*16+m)*72 + qd*8], acc);
            acc = MFMA16(a1, *(bf16x8*)&vt[(nt*16+m)*72 + 32 + qd*8], acc);
            #pragma unroll
            for (int r=0;r<4;r++)
                dsT[(nt*16+m)*68 + ft*16 + qd*4 + r] = acc[r];
        }
    }
    if (tid >= 256){
        const int t2 = tid - 256;
        const int f = t2 & 63, sg = t2 >> 6;
        bf16x8 x0 = *(bf16x8*)&kt[f*72 + sg*16];
        bf16x8 x1 = *(bf16x8*)&kt[f*72 + sg*16 + 8];
        float sm = 0.f;
        #pragma unroll
        for (int j=0;j<8;j++) sm += (float)x0[j] + (float)x1[j];
        part[sg*64 + f] = sm;
    }
    __syncthreads();
    if (tid < 256){
        const int d = tid >> 2, F = (tid & 3) * 16;
        float* dst = CST + ((size_t)bid*64 + d)*64 + F;
        #pragma unroll
        for (int j=0;j<4;j++)
            *(float4*)(dst + 4*j) = *(float4*)&dsT[d*68 + F + 4*j];
    } else if (tid < 320){
        const int f = tid - 256;
        KCS[(size_t)bid*64 + f] = part[f] + part[64+f] + part[128+f] + part[192+f];
    }
    gsync(syncc, 1);

    // ================= P2: exclusive chunk prefix (CST/KCS) =================
    if (tid < 64){
        const int e4 = ch*64 + tid;   // float4 column within bh's 1024
        float4 vals[16];
        #pragma unroll
        for (int c=0;c<NCH;c++)
            vals[c] = ((float4*)(CST + ((size_t)(bh*NCH + c))*4096))[e4];
        float4 run = {0.f,0.f,0.f,0.f};
        #pragma unroll
        for (int c=0;c<NCH;c++){
            ((float4*)(CST + ((size_t)(bh*NCH + c))*4096))[e4] = run;
            run.x += vals[c].x; run.y += vals[c].y; run.z += vals[c].z; run.w += vals[c].w;
        }
    } else if (ch == 0 && tid < 128){
        const int f = tid - 64;
        float kv[16];
        #pragma unroll
        for (int c=0;c<NCH;c++) kv[c] = KCS[((size_t)(bh*NCH + c))*64 + f];
        float r = 0.f;
        #pragma unroll
        for (int c=0;c<NCH;c++){ KCS[((size_t)(bh*NCH + c))*64 + f] = r; r += kv[c]; }
    }
    gsync(syncc, 2);

    // ================= P3: per-chunk causal attention =================
    // S1: kt (bf16 [f][s]) -> kct (fp32, stride 67)
    if (tid < 256){
        const int f = tid >> 2, sg = tid & 3;
        bf16x8 x0 = *(bf16x8*)&kt[f*72 + sg*16];
        bf16x8 x1 = *(bf16x8*)&kt[f*72 + sg*16 + 8];
        #pragma unroll
        for (int j=0;j<8;j++){
            kct[f*67 + sg*16 + j]     = (float)x0[j];
            kct[f*67 + sg*16 + 8 + j] = (float)x1[j];
        }
    }
    __syncthreads();
    // S2: inclusive scan along s per f, seeded with exclusive KCS
    {
        const int f2 = tid >> 2, sg2 = tid & 3;
        float v16[16];
        if (tid < 256){
            #pragma unroll
            for (int j=0;j<16;j++) v16[j] = kct[f2*67 + sg2*16 + j];
            #pragma unroll
            for (int j=1;j<16;j++) v16[j] += v16[j-1];
            part[f2*4 + sg2] = v16[15];
        }
        __syncthreads();
        if (tid < 256){
            float offs = KCS[(size_t)bid*64 + f2];
            if (sg2 > 0) offs += part[f2*4 + 0];
            if (sg2 > 1) offs += part[f2*4 + 1];
            if (sg2 > 2) offs += part[f2*4 + 2];
            #pragma unroll
            for (int j=0;j<16;j++) kct[f2*67 + sg2*16 + j] = offs + v16[j];
        }
    }
    __syncthreads();
    // S3: qn = phi_q / kcum -> qnl bf16 [s][f]
    if (tid < 256){
        const int sr = tid >> 2, F = (tid & 3) * 16;
        bf16x8 x0 = *(bf16x8*)&phql[sr*72 + F];
        bf16x8 x1 = *(bf16x8*)&phql[sr*72 + F + 8];
        bf16x8 o0, o1;
        #pragma unroll
        for (int j=0;j<8;j++){
            o0[j] = (__bf16)((float)x0[j] / kct[(F+j)*67 + sr]);
            o1[j] = (__bf16)((float)x1[j] / kct[(F+8+j)*67 + sr]);
        }
        *(bf16x8*)&qnl[sr*72 + F]     = o0;
        *(bf16x8*)&qnl[sr*72 + F + 8] = o1;
    }
    __syncthreads();

    const int rt = ww, np = (w >> 2) * 2;
    bf16x8 qa0 = *(bf16x8*)&qnl[(rt*16+m)*72 + qd*8];
    bf16x8 qa1 = *(bf16x8*)&qnl[(rt*16+m)*72 + 32 + qd*8];

    // S4: S = tril(qn @ phi_k^T) -> sAl (overwrites kt region; kt consumed in S1)
    #pragma unroll
    for (int j=0;j<2;j++){
        const int nt = np + j;
        f32x4 acc = {0.f,0.f,0.f,0.f};
        acc = MFMA16(qa0, *(const bf16x8*)&phkl[(nt*16+m)*72 + qd*8], acc);
        acc = MFMA16(qa1, *(const bf16x8*)&phkl[(nt*16+m)*72 + 32 + qd*8], acc);
        const int t_loc = nt*16 + m;
        #pragma unroll
        for (int r=0;r<4;r++){
            const int s_loc = rt*16 + qd*4 + r;
            float v = (t_loc <= s_loc) ? acc[r] : 0.f;
            sAl[s_loc*72 + t_loc] = (__bf16)v;
        }
    }
    __syncthreads();

    {
        bf16x8 sa0 = *(bf16x8*)&sAl[(rt*16+m)*72 + qd*8];
        bf16x8 sa1 = *(bf16x8*)&sAl[(rt*16+m)*72 + 32 + qd*8];
        // S5: O = S@v' + qn@P
        #pragma unroll
        for (int j=0;j<2;j++){
            const int nt = np + j;
            const int d = nt*16 + m;
            const float* pp = CST + ((size_t)bid*64 + d)*64;
            f32x4 acc = {0.f,0.f,0.f,0.f};
            acc = MFMA16(sa0, *(const bf16x8*)&vt[d*72 + qd*8], acc);
            acc = MFMA16(sa1, *(const bf16x8*)&vt[d*72 + 32 + qd*8], acc);
            acc = MFMA16(qa0, cvt_f32x8(pp + qd*8), acc);
            acc = MFMA16(qa1, cvt_f32x8(pp + 32 + qd*8), acc);
            #pragma unroll
            for (int r=0;r<4;r++)
                O[((size_t)bh*SS + s0 + rt*16 + qd*4 + r)*DD + d] = (__bf16)acc[r];
        }
    }
    gsync(syncc, 3);

    // ================= P4: output FC =================
    {
        const int rb = bid >> 3, cb = bid & 7;
        const int rw = ww, cpair = (w >> 2) * 2;
        const int r0 = rb*64 + rw*16;
        f32x4 acc[2];
        #pragma unroll
        for (int j=0;j<2;j++){
            float bb = bfc[cb*64 + (cpair+j)*16 + m];
            acc[j][0]=bb; acc[j][1]=bb; acc[j][2]=bb; acc[j][3]=bb;
        }
        const int row = r0 + m;
        const int b2 = row >> 10, s2 = row & 1023;
        #pragma unroll 4
        for (int c=0;c<16;c++){
            const int hc = c >> 1;
            const int doff = (c & 1)*32 + qd*8;
            bf16x8 a = *(const bf16x8*)(O + ((size_t)((b2*HH + hc)*SS + s2))*DD + doff);
            #pragma unroll
            for (int j=0;j<2;j++){
                bf16x8 bfr = *(const bf16x8*)(WfcB + (size_t)(cb*64 + (cpair+j)*16 + m)*DM + c*32 + qd*8);
                acc[j] = MFMA16(a, bfr, acc[j]);
            }
        }
        #pragma unroll
        for (int j=0;j<2;j++){
            #pragma unroll
            for (int r=0;r<4;r++){
                const int rr = r0 + qd*4 + r;
                out[(size_t)rr*DM + cb*64 + (cpair+j)*16 + m] = acc[j][r];
            }
        }
    }
}

extern "C" void kernel_launch(void* const* d_in, const int* in_sizes, int n_in,
                              void* d_out, int out_size, void* d_ws, size_t ws_size,
                              hipStream_t stream) {
    const float* q_in  = (const float*)d_in[0];
    const float* k_in  = (const float*)d_in[1];
    const float* v_in  = (const float*)d_in[2];
    const float* Wq    = (const float*)d_in[3];
    const float* bq    = (const float*)d_in[4];
    const float* Wk    = (const float*)d_in[5];
    const float* bk    = (const float*)d_in[6];
    const float* Wv    = (const float*)d_in[7];
    const float* bv    = (const float*)d_in[8];
    const float* orf_q = (const float*)d_in[9];
    const float* orf_k = (const float*)d_in[10];
    const float* Wfc   = (const float*)d_in[11];
    const float* bfc   = (const float*)d_in[12];

    unsigned* syncc = (unsigned*)d_ws;           // 16 slots (64 B used, 256 B reserved)
    float* CST  = (float*)d_ws + 64;             // 1048576 f32
    float* KCS  = CST + 1048576;                 // 16384 f32
    float* cq   = KCS + 16384;
    float* ck   = cq + 64;
    bf16_t* Mtq  = (bf16_t*)(ck + 64);           // 4096 bf16
    bf16_t* Mtk  = Mtq + 4096;
    bf16_t* WvB  = Mtk + 4096;
    bf16_t* WfcB = WvB + 4096;                   // 262144 bf16
    bf16_t* O    = WfcB + 262144;                // 1048576 bf16

    hipMemsetAsync(d_ws, 0, 256, stream);
    hipLaunchKernelGGL(kfused, dim3(256), dim3(512), 0, stream,
                       q_in, k_in, v_in, Wq, bq, Wk, bk, Wv, bv, orf_q, orf_k,
                       Wfc, bfc, Mtq, Mtk, cq, ck, WvB, WfcB, CST, KCS, O,
                       syncc, (float*)d_out);
}

// Round 8
// 133.229 us; speedup vs baseline: 1.8522x; 1.8522x over previous
//
#include <hip/hip_runtime.h>

// FastAttention (Performer-style, causal) on MI355X — bf16 MFMA, 4-dispatch pipeline.
// B=2, S=1024, H=8, DEPTH=64, NFEAT=64, D_MODEL=512. fp32 in/out.
//
//  kfuse: Mt = norm*(ORF@W) [f][d] bf16, c = norm*(ORF@b); Wv,Wfc -> bf16
//  kproj: 512 thr: q-proj ∥ k-proj, then PHI_KT-store ∥ v-proj, then fused
//         per-chunk sums CST[d][f] (fp32), KCS[f] via MFMA from LDS
//  kattn: 512 thr: waves 4-7 sum exclusive prefix P from CST inline (fp32, same
//         order as the old kprefix) while waves 0-3 stage the kcum scan; then
//         qn = phi_q/kcum, S = tril(qn@phi_k^T), O = S@v' + qn@P
//  kfc:   512 thr, out = O@Wfc^T + bfc (2048x512x512 MFMA)
// (R7's fused single kernel with grid barriers: 247us — barriers ~40us each. Reverted.)

#define SS 1024
#define HH 8
#define DD 64
#define FF 64
#define DM 512
#define NCH 16

typedef __bf16 bf16_t;
typedef __attribute__((ext_vector_type(8))) __bf16 bf16x8;
typedef __attribute__((ext_vector_type(4))) __bf16 bf16x4;
typedef __attribute__((ext_vector_type(4))) float f32x4;

#define MFMA16(a,b,c) __builtin_amdgcn_mfma_f32_16x16x32_bf16((a),(b),(c),0,0,0)

__device__ inline bf16x8 cvt_f32x8(const float* p){
    const float4* p4 = (const float4*)p;
    float4 x = p4[0], y = p4[1];
    bf16x8 r;
    r[0]=(__bf16)x.x; r[1]=(__bf16)x.y; r[2]=(__bf16)x.z; r[3]=(__bf16)x.w;
    r[4]=(__bf16)y.x; r[5]=(__bf16)y.y; r[6]=(__bf16)y.z; r[7]=(__bf16)y.w;
    return r;
}

// ---------------- kfuse: weight fusion + bf16 conversion ----------------
__global__ __launch_bounds__(256) void kfuse(
    const float* __restrict__ orf_q, const float* __restrict__ orf_k,
    const float* __restrict__ Wq, const float* __restrict__ bq,
    const float* __restrict__ Wk, const float* __restrict__ bk,
    const float* __restrict__ Wv, const float* __restrict__ Wfc,
    bf16_t* __restrict__ Mtq, bf16_t* __restrict__ Mtk,
    float* __restrict__ cq, float* __restrict__ ck,
    bf16_t* __restrict__ WvB, bf16_t* __restrict__ WfcB)
{
    const int tid = threadIdx.x, bid = blockIdx.x;
    if (bid < 2) {
        const float* ORF = bid ? orf_k : orf_q;
        const float* W   = bid ? Wk : Wq;
        const float* bb  = bid ? bk : bq;
        bf16_t* Mt = bid ? Mtk : Mtq;
        float* cc  = bid ? ck : cq;
        const float norm = 0.35355339059327373f; // 64^-0.25
        const int f = tid >> 2, d0 = (tid & 3) * 16;
        float acc[16];
        #pragma unroll
        for (int j=0;j<16;j++) acc[j]=0.f;
        float bacc = 0.f;
        for (int e=0;e<64;e++){
            float oe = ORF[f*64+e];
            const float* wr = W + e*64 + d0;
            #pragma unroll
            for (int j=0;j<16;j++) acc[j] += oe*wr[j];
            bacc += oe*bb[e];
        }
        #pragma unroll
        for (int j=0;j<16;j++) Mt[f*64+d0+j] = (__bf16)(norm*acc[j]);
        if ((tid&3)==0) cc[f] = norm*bacc;
    } else if (bid == 2) {
        for (int i=tid;i<4096;i+=256) WvB[i] = (__bf16)Wv[i];
    } else {
        const float4* W4 = (const float4*)Wfc;
        for (int i=(bid-3)*256+tid; i<65536; i+=13*256){
            float4 v = W4[i];
            bf16x4 o; o[0]=(__bf16)v.x; o[1]=(__bf16)v.y; o[2]=(__bf16)v.z; o[3]=(__bf16)v.w;
            *(bf16x4*)(WfcB + 4*i) = o;
        }
    }
}

// ---------------- kproj: q/k/v proj + feature map + fused chunk sums ----------------
// grid = 256 (bh*16 + ch), 512 threads (8 waves).
__global__ __launch_bounds__(512) void kproj(
    const float* __restrict__ q_in, const float* __restrict__ k_in,
    const float* __restrict__ v_in,
    const bf16_t* __restrict__ Mtq, const float* __restrict__ cq,
    const bf16_t* __restrict__ Mtk, const float* __restrict__ ck,
    const bf16_t* __restrict__ WvB, const float* __restrict__ bv,
    bf16_t* __restrict__ PHI_Q, bf16_t* __restrict__ PHI_K,
    bf16_t* __restrict__ PHI_KT, bf16_t* __restrict__ VPT,
    float* __restrict__ CST, float* __restrict__ KCS)
{
    __shared__ bf16_t kt[64*72];   // phi_k^T  [f][s_local]
    __shared__ bf16_t vt[64*72];   // v'^T     [d][s_local]
    __shared__ float dsT[64*68];   // chunk sum [d][f]
    __shared__ float part[256];
    const int tid = threadIdx.x;
    const int l = tid & 63;
    const int w = __builtin_amdgcn_readfirstlane(tid >> 6);   // 0..7
    const int ww = w & 3;
    const int qd = l >> 4, m = l & 15;
    const int bid = blockIdx.x;
    const int bh = bid >> 4, ch = bid & 15;
    const int b = bh >> 3, h = bh & 7;
    const int s0 = ch*64;
    const int sw = s0 + ww*16;

    // ---- Phase 1: waves 0-3 q-proj, waves 4-7 k-proj ----
    if (w < 4) {
        const float* xp = q_in + ((size_t)(b*SS + sw + m))*DM + h*DD;
        bf16x8 a0 = cvt_f32x8(xp + qd*8);
        bf16x8 a1 = cvt_f32x8(xp + 32 + qd*8);
        #pragma unroll
        for (int nt=0;nt<4;nt++){
            const int f = nt*16 + m;
            float cb = cq[f];
            f32x4 acc = {cb,cb,cb,cb};
            acc = MFMA16(a0, *(const bf16x8*)(Mtq + f*64 + qd*8), acc);
            acc = MFMA16(a1, *(const bf16x8*)(Mtq + f*64 + 32 + qd*8), acc);
            #pragma unroll
            for (int r=0;r<4;r++){
                float v = acc[r];
                v = (v>0.f)?v:0.f; v += 0.001f;
                PHI_Q[((size_t)bh*SS + sw + qd*4 + r)*FF + f] = (__bf16)v;
            }
        }
    } else {
        const float* xp = k_in + ((size_t)(b*SS + sw + m))*DM + h*DD;
        bf16x8 a0 = cvt_f32x8(xp + qd*8);
        bf16x8 a1 = cvt_f32x8(xp + 32 + qd*8);
        #pragma unroll
        for (int nt=0;nt<4;nt++){
            const int f = nt*16 + m;
            float cb = ck[f];
            f32x4 acc = {cb,cb,cb,cb};
            acc = MFMA16(a0, *(const bf16x8*)(Mtk + f*64 + qd*8), acc);
            acc = MFMA16(a1, *(const bf16x8*)(Mtk + f*64 + 32 + qd*8), acc);
            #pragma unroll
            for (int r=0;r<4;r++){
                float v = acc[r];
                v = (v>0.f)?v:0.f; v += 0.001f;
                __bf16 h16 = (__bf16)v;
                PHI_K[((size_t)bh*SS + sw + qd*4 + r)*FF + f] = h16;
                kt[f*72 + ww*16 + qd*4 + r] = h16;
            }
        }
    }
    __syncthreads();

    // ---- Phase 2: tid<256 store PHI_KT; waves 4-7 v-proj -> vt ----
    if (tid < 256) {
        const int f = tid >> 2, sg = tid & 3;
        bf16x8 v0 = *(bf16x8*)&kt[f*72 + sg*16];
        bf16x8 v1 = *(bf16x8*)&kt[f*72 + sg*16 + 8];
        bf16_t* dst = PHI_KT + ((size_t)bh*64 + f)*SS + s0 + sg*16;
        *(bf16x8*)dst = v0; *(bf16x8*)(dst+8) = v1;
    } else {
        const float* xp = v_in + ((size_t)(b*SS + sw + m))*DM + h*DD;
        bf16x8 a0 = cvt_f32x8(xp + qd*8);
        bf16x8 a1 = cvt_f32x8(xp + 32 + qd*8);
        #pragma unroll
        for (int nt=0;nt<4;nt++){
            const int e = nt*16 + m;
            float cb = bv[e];
            f32x4 acc = {cb,cb,cb,cb};
            acc = MFMA16(a0, *(const bf16x8*)(WvB + e*64 + qd*8), acc);
            acc = MFMA16(a1, *(const bf16x8*)(WvB + e*64 + 32 + qd*8), acc);
            #pragma unroll
            for (int r=0;r<4;r++)
                vt[e*72 + ww*16 + qd*4 + r] = (__bf16)acc[r];
        }
    }
    __syncthreads();

    // ---- Phase 3: chunk-sum MFMA (8 waves, ft x nt split) + VPT store + colsums ----
    {
        const int ft = ww, np = (w >> 2) * 2;
        bf16x8 a0 = *(bf16x8*)&kt[(ft*16+m)*72 + qd*8];
        bf16x8 a1 = *(bf16x8*)&kt[(ft*16+m)*72 + 32 + qd*8];
        #pragma unroll
        for (int j=0;j<2;j++){
            const int nt = np + j;
            f32x4 acc = {0.f,0.f,0.f,0.f};
            acc = MFMA16(a0, *(bf16x8*)&vt[(nt*16+m)*72 + qd*8], acc);
            acc = MFMA16(a1, *(bf16x8*)&vt[(nt*16+m)*72 + 32 + qd*8], acc);
            #pragma unroll
            for (int r=0;r<4;r++)
                dsT[(nt*16+m)*68 + ft*16 + qd*4 + r] = acc[r];
        }
    }
    if (tid < 256) {
        const int d = tid >> 2, sg = tid & 3;
        bf16x8 v0 = *(bf16x8*)&vt[d*72 + sg*16];
        bf16x8 v1 = *(bf16x8*)&vt[d*72 + sg*16 + 8];
        bf16_t* dst = VPT + ((size_t)bh*64 + d)*SS + s0 + sg*16;
        *(bf16x8*)dst = v0; *(bf16x8*)(dst+8) = v1;
    } else {
        const int t2 = tid - 256;
        const int f = t2 & 63, sg = t2 >> 6;
        bf16x8 x0 = *(bf16x8*)&kt[f*72 + sg*16];
        bf16x8 x1 = *(bf16x8*)&kt[f*72 + sg*16 + 8];
        float sm = 0.f;
        #pragma unroll
        for (int j=0;j<8;j++) sm += (float)x0[j] + (float)x1[j];
        part[sg*64 + f] = sm;
    }
    __syncthreads();

    // ---- Phase 4: CST (this chunk's raw sum) + KCS stores ----
    if (tid < 256) {
        const int d = tid >> 2, F = (tid & 3) * 16;
        float* dst = CST + ((size_t)bid*64 + d)*64 + F;
        #pragma unroll
        for (int j=0;j<4;j++)
            *(float4*)(dst + 4*j) = *(float4*)&dsT[d*68 + F + 4*j];
    } else if (tid < 320) {
        const int f = tid - 256;
        KCS[(size_t)bid*64 + f] = part[f] + part[64+f] + part[128+f] + part[192+f];
    }
}

// ---------------- kattn: per-chunk causal attention, inline exclusive prefix ----------------
// grid = 256 (bh*16+ch), 512 threads. Waves 4-7: P = sum_{cc<ch} CST[cc] (fp32, same
// order as old kprefix) -> pT bf16 [d][f]; waves 0-3: kcum scan staging. No kprefix kernel.
__global__ __launch_bounds__(512) void kattn(
    const bf16_t* __restrict__ PHI_Q, const bf16_t* __restrict__ PHI_K,
    const bf16_t* __restrict__ PHI_KT, const bf16_t* __restrict__ VPT,
    const float* __restrict__ CST, const float* __restrict__ KCS,
    bf16_t* __restrict__ O)
{
    __shared__ float kct[64*67];    // [f][s] kcum
    __shared__ bf16_t qnl[64*72];   // [s][f] qn
    __shared__ bf16_t sAl[64*72];   // [s][t] masked scores
    __shared__ bf16_t pT[64*72];    // [d][f] exclusive-prefix P (bf16)
    __shared__ float scanp[256];
    __shared__ float kcsp[64];
    const int tid = threadIdx.x;
    const int l = tid & 63;
    const int w = __builtin_amdgcn_readfirstlane(tid >> 6);  // 0..7
    const int rt = w & 3;            // row-tile
    const int np = (w >> 2) * 2;     // nt-pair start
    const int qd = l >> 4, m = l & 15;
    const int bid = blockIdx.x;
    const int bh = bid >> 4, ch = bid & 15;
    const int cs0 = ch*64;

    if (tid >= 256) {
        // ---- Phase A: exclusive prefix P over earlier chunks (fp32 acc) ----
        const int t2 = tid - 256;
        const int base = t2 * 16;
        const int d = t2 >> 2, f0 = (t2 & 3) * 16;
        float acc[16];
        #pragma unroll
        for (int j=0;j<16;j++) acc[j]=0.f;
        for (int cc = 0; cc < ch; cc++) {
            const float4* p = (const float4*)(CST + ((size_t)(bh*NCH + cc))*4096 + base);
            #pragma unroll
            for (int j=0;j<4;j++){
                float4 t = p[j];
                acc[4*j]+=t.x; acc[4*j+1]+=t.y; acc[4*j+2]+=t.z; acc[4*j+3]+=t.w;
            }
        }
        bf16x8 o0, o1;
        #pragma unroll
        for (int j=0;j<8;j++){ o0[j]=(__bf16)acc[j]; o1[j]=(__bf16)acc[8+j]; }
        *(bf16x8*)&pT[d*72 + f0]     = o0;
        *(bf16x8*)&pT[d*72 + f0 + 8] = o1;
    } else {
        // ---- S1: phi_k^T chunk -> kct fp32; tid<64 also: KCS exclusive prefix ----
        const int f = tid >> 2, sg = tid & 3;
        const bf16_t* kp = PHI_KT + ((size_t)bh*64 + f)*SS + cs0 + sg*16;
        bf16x8 x0 = *(const bf16x8*)kp;
        bf16x8 x1 = *(const bf16x8*)(kp+8);
        #pragma unroll
        for (int j=0;j<8;j++){
            kct[f*67 + sg*16 + j]     = (float)x0[j];
            kct[f*67 + sg*16 + 8 + j] = (float)x1[j];
        }
        if (tid < 64) {
            float r = 0.f;
            for (int cc = 0; cc < ch; cc++) r += KCS[((size_t)(bh*NCH + cc))*64 + tid];
            kcsp[tid] = r;
        }
    }
    __syncthreads();

    // S2: inclusive scan along s per f, seeded with exclusive kcsp
    const int f2 = tid >> 2, sg2 = tid & 3;
    float v16[16];
    if (tid < 256) {
        #pragma unroll
        for (int j=0;j<16;j++) v16[j] = kct[f2*67 + sg2*16 + j];
        #pragma unroll
        for (int j=1;j<16;j++) v16[j] += v16[j-1];
        scanp[f2*4 + sg2] = v16[15];
    }
    __syncthreads();
    if (tid < 256) {
        float offs = kcsp[f2];
        if (sg2 > 0) offs += scanp[f2*4 + 0];
        if (sg2 > 1) offs += scanp[f2*4 + 1];
        if (sg2 > 2) offs += scanp[f2*4 + 2];
        #pragma unroll
        for (int j=0;j<16;j++) kct[f2*67 + sg2*16 + j] = offs + v16[j];
    }
    __syncthreads();

    // S3: qn = phi_q / kcum -> qnl bf16 [s][f]
    if (tid < 256) {
        const int sr = tid >> 2, F = (tid & 3) * 16;
        const bf16_t* qp = PHI_Q + ((size_t)bh*SS + cs0 + sr)*FF + F;
        bf16x8 x0 = *(const bf16x8*)qp;
        bf16x8 x1 = *(const bf16x8*)(qp+8);
        bf16x8 o0, o1;
        #pragma unroll
        for (int j=0;j<8;j++){
            o0[j] = (__bf16)((float)x0[j] / kct[(F+j)*67 + sr]);
            o1[j] = (__bf16)((float)x1[j] / kct[(F+8+j)*67 + sr]);
        }
        *(bf16x8*)&qnl[sr*72 + F]     = o0;
        *(bf16x8*)&qnl[sr*72 + F + 8] = o1;
    }
    __syncthreads();

    bf16x8 qa0 = *(bf16x8*)&qnl[(rt*16+m)*72 + qd*8];
    bf16x8 qa1 = *(bf16x8*)&qnl[(rt*16+m)*72 + 32 + qd*8];

    // S4: S = tril(qn @ phi_k^T); wave handles t-tiles {np, np+1}
    #pragma unroll
    for (int j=0;j<2;j++){
        const int nt = np + j;
        const bf16_t* kb = PHI_K + ((size_t)bh*SS + cs0 + nt*16 + m)*FF;
        f32x4 acc = {0.f,0.f,0.f,0.f};
        acc = MFMA16(qa0, *(const bf16x8*)(kb + qd*8), acc);
        acc = MFMA16(qa1, *(const bf16x8*)(kb + 32 + qd*8), acc);
        const int t_loc = nt*16 + m;
        #pragma unroll
        for (int r=0;r<4;r++){
            const int s_loc = rt*16 + qd*4 + r;
            float v = (t_loc <= s_loc) ? acc[r] : 0.f;
            sAl[s_loc*72 + t_loc] = (__bf16)v;
        }
    }
    __syncthreads();

    bf16x8 sa0 = *(bf16x8*)&sAl[(rt*16+m)*72 + qd*8];
    bf16x8 sa1 = *(bf16x8*)&sAl[(rt*16+m)*72 + 32 + qd*8];

    // S5: O = S@v' + qn@P; wave handles d-tiles {np, np+1}
    #pragma unroll
    for (int j=0;j<2;j++){
        const int nt = np + j;
        const int d = nt*16 + m;
        const bf16_t* vb = VPT + ((size_t)bh*64 + d)*SS + cs0;
        f32x4 acc = {0.f,0.f,0.f,0.f};
        acc = MFMA16(sa0, *(const bf16x8*)(vb + qd*8), acc);
        acc = MFMA16(sa1, *(const bf16x8*)(vb + 32 + qd*8), acc);
        acc = MFMA16(qa0, *(const bf16x8*)&pT[d*72 + qd*8], acc);
        acc = MFMA16(qa1, *(const bf16x8*)&pT[d*72 + 32 + qd*8], acc);
        #pragma unroll
        for (int r=0;r<4;r++)
            O[((size_t)bh*SS + cs0 + rt*16 + qd*4 + r)*DD + d] = (__bf16)acc[r];
    }
}

// ---------------- kfc: out = O @ Wfc^T + bfc (512 thr, 8-wave split) ----------------
// grid = 32 rowtiles * 8 coltiles = 256 blocks, 512 threads.
__global__ __launch_bounds__(512) void kfc(
    const bf16_t* __restrict__ O, const bf16_t* __restrict__ WfcB,
    const float* __restrict__ bfc, float* __restrict__ out)
{
    const int tid = threadIdx.x;
    const int l = tid & 63;
    const int w = __builtin_amdgcn_readfirstlane(tid >> 6);  // 0..7
    const int rw = w & 3, cpair = (w >> 2) * 2;
    const int qd = l >> 4, m = l & 15;
    const int bid = blockIdx.x;
    const int rb = bid >> 3, cb = bid & 7;
    const int r0 = rb*64 + rw*16;

    f32x4 acc[2];
    #pragma unroll
    for (int j=0;j<2;j++){
        float bb = bfc[cb*64 + (cpair+j)*16 + m];
        acc[j][0]=bb; acc[j][1]=bb; acc[j][2]=bb; acc[j][3]=bb;
    }
    const int row = r0 + m;
    const int b = row >> 10, s = row & 1023;
    #pragma unroll 4
    for (int c=0;c<16;c++){
        const int h = c >> 1;
        const int doff = (c & 1)*32 + qd*8;
        bf16x8 a = *(const bf16x8*)(O + ((size_t)((b*HH + h)*SS + s))*DD + doff);
        #pragma unroll
        for (int j=0;j<2;j++){
            bf16x8 bfr = *(const bf16x8*)(WfcB + (size_t)(cb*64 + (cpair+j)*16 + m)*DM + c*32 + qd*8);
            acc[j] = MFMA16(a, bfr, acc[j]);
        }
    }
    #pragma unroll
    for (int j=0;j<2;j++){
        #pragma unroll
        for (int r=0;r<4;r++){
            const int rr = r0 + qd*4 + r;
            out[(size_t)rr*DM + cb*64 + (cpair+j)*16 + m] = acc[j][r];
        }
    }
}

extern "C" void kernel_launch(void* const* d_in, const int* in_sizes, int n_in,
                              void* d_out, int out_size, void* d_ws, size_t ws_size,
                              hipStream_t stream) {
    const float* q_in  = (const float*)d_in[0];
    const float* k_in  = (const float*)d_in[1];
    const float* v_in  = (const float*)d_in[2];
    const float* Wq    = (const float*)d_in[3];
    const float* bq    = (const float*)d_in[4];
    const float* Wk    = (const float*)d_in[5];
    const float* bk    = (const float*)d_in[6];
    const float* Wv    = (const float*)d_in[7];
    const float* bv    = (const float*)d_in[8];
    const float* orf_q = (const float*)d_in[9];
    const float* orf_k = (const float*)d_in[10];
    const float* Wfc   = (const float*)d_in[11];
    const float* bfc   = (const float*)d_in[12];

    float* CST   = (float*)d_ws;                 // 1048576 fp32 (raw per-chunk sums)
    float* KCS   = CST + 1048576;                // 16384 fp32 (raw per-chunk colsums)
    float* cq    = KCS + 16384;
    float* ck    = cq + 64;
    bf16_t* PHI_Q  = (bf16_t*)(ck + 64);         // 1M bf16 each
    bf16_t* PHI_K  = PHI_Q + 1048576;
    bf16_t* PHI_KT = PHI_K + 1048576;
    bf16_t* VPT    = PHI_KT + 1048576;
    bf16_t* O      = VPT + 1048576;
    bf16_t* Mtq    = O + 1048576;
    bf16_t* Mtk    = Mtq + 4096;
    bf16_t* WvB    = Mtk + 4096;
    bf16_t* WfcB   = WvB + 4096;                 // 262144

    kfuse<<<16, 256, 0, stream>>>(orf_q, orf_k, Wq, bq, Wk, bk, Wv, Wfc,
                                  Mtq, Mtk, cq, ck, WvB, WfcB);
    kproj<<<256, 512, 0, stream>>>(q_in, k_in, v_in, Mtq, cq, Mtk, ck, WvB, bv,
                                   PHI_Q, PHI_K, PHI_KT, VPT, CST, KCS);
    kattn<<<256, 512, 0, stream>>>(PHI_Q, PHI_K, PHI_KT, VPT, CST, KCS, O);
    kfc<<<256, 512, 0, stream>>>(O, WfcB, bfc, (float*)d_out);
}

// Round 9
// 131.819 us; speedup vs baseline: 1.8720x; 1.0107x over previous
//
#include <hip/hip_runtime.h>

// FastAttention (Performer-style, causal) on MI355X — bf16 MFMA, 3-dispatch pipeline.
// B=2, S=1024, H=8, DEPTH=64, NFEAT=64, D_MODEL=512. fp32 in/out.
//
//  kproj: per-block fp32 recompute of fused weights Mt = norm*(ORF@W) (same
//         accumulation order as the old kfuse -> bit-identical), WvB bf16 in LDS,
//         WfcB bf16 conversion spread across blocks; then q/k/v proj + feature map
//         + per-chunk sums CST[d][f], KCS[f] (MFMA from LDS).
//  kattn: waves 4-7 sum exclusive prefix P from CST inline while waves 0-3 stage
//         the kcum scan; qn = phi_q/kcum, S = tril(qn@phi_k^T), O = S@v' + qn@P
//  kfc:   out = O@Wfc^T + bfc (2048x512x512 MFMA, reads WfcB from kproj)
// History: 6/5/4-dispatch variants all ~133us (harness floor ~110us: 268MB ws
// re-poison fill ~44us + 13 input-restore copies + graph overhead). R7 single
// kernel + grid barriers: 247us (barriers ~40us each) — do not revisit.

#define SS 1024
#define HH 8
#define DD 64
#define FF 64
#define DM 512
#define NCH 16

typedef __bf16 bf16_t;
typedef __attribute__((ext_vector_type(8))) __bf16 bf16x8;
typedef __attribute__((ext_vector_type(4))) __bf16 bf16x4;
typedef __attribute__((ext_vector_type(4))) float f32x4;

#define MFMA16(a,b,c) __builtin_amdgcn_mfma_f32_16x16x32_bf16((a),(b),(c),0,0,0)

__device__ inline bf16x8 pack8(float4 x, float4 y){
    bf16x8 r;
    r[0]=(__bf16)x.x; r[1]=(__bf16)x.y; r[2]=(__bf16)x.z; r[3]=(__bf16)x.w;
    r[4]=(__bf16)y.x; r[5]=(__bf16)y.y; r[6]=(__bf16)y.z; r[7]=(__bf16)y.w;
    return r;
}

// ---------------- kproj: weight prep + q/k/v proj + feature map + chunk sums ----------------
// grid = 256 (bh*16 + ch), 512 threads (8 waves).
__global__ __launch_bounds__(512) void kproj(
    const float* __restrict__ q_in, const float* __restrict__ k_in,
    const float* __restrict__ v_in,
    const float* __restrict__ Wq, const float* __restrict__ bq,
    const float* __restrict__ Wk, const float* __restrict__ bk,
    const float* __restrict__ Wv, const float* __restrict__ bv,
    const float* __restrict__ orf_q, const float* __restrict__ orf_k,
    const float* __restrict__ Wfc,
    bf16_t* __restrict__ PHI_Q, bf16_t* __restrict__ PHI_K,
    bf16_t* __restrict__ PHI_KT, bf16_t* __restrict__ VPT,
    float* __restrict__ CST, float* __restrict__ KCS,
    bf16_t* __restrict__ WfcB)
{
    __shared__ bf16_t Mtq_l[64*72];  // fused q weights [f][d], stride 72 (2-way free)
    __shared__ bf16_t Mtk_l[64*72];
    __shared__ bf16_t WvB_l[64*72];  // Wv bf16 [e][d]
    __shared__ float cql[64], ckl[64];
    __shared__ bf16_t kt[64*72];     // phi_k^T [f][s_local]
    __shared__ bf16_t vt[64*72];     // v'^T    [d][s_local]
    __shared__ float dsT[64*68];     // chunk sum [d][f]
    __shared__ float part[256];
    const int tid = threadIdx.x;
    const int l = tid & 63;
    const int w = __builtin_amdgcn_readfirstlane(tid >> 6);   // 0..7
    const int ww = w & 3;
    const int qd = l >> 4, m = l & 15;
    const int bid = blockIdx.x;
    const int bh = bid >> 4, ch = bid & 15;
    const int b = bh >> 3, h = bh & 7;
    const int s0 = ch*64;
    const int sw = s0 + ww*16;

    // ---- preload this block's input rows (overlaps weight prep) ----
    const float* xrow = ((w < 4) ? q_in : k_in) + ((size_t)(b*SS + sw + m))*DM + h*DD;
    float4 pA0 = *(const float4*)(xrow + qd*8);
    float4 pA1 = *(const float4*)(xrow + qd*8 + 4);
    float4 pB0 = *(const float4*)(xrow + 32 + qd*8);
    float4 pB1 = *(const float4*)(xrow + 32 + qd*8 + 4);
    float4 vA0 = {0,0,0,0}, vA1 = {0,0,0,0}, vB0 = {0,0,0,0}, vB1 = {0,0,0,0};
    if (w >= 4){
        const float* vrow = v_in + ((size_t)(b*SS + sw + m))*DM + h*DD;
        vA0 = *(const float4*)(vrow + qd*8);
        vA1 = *(const float4*)(vrow + qd*8 + 4);
        vB0 = *(const float4*)(vrow + 32 + qd*8);
        vB1 = *(const float4*)(vrow + 32 + qd*8 + 4);
    }

    // ---- Phase 0: fused weights (fp32, ascending-e order == old kfuse, bit-identical) ----
    {
        const float norm = 0.35355339059327373f; // 64^-0.25
        const int f = tid >> 3, d0 = (tid & 7) * 8;
        float accq[8], acck[8];
        #pragma unroll
        for (int j=0;j<8;j++){ accq[j]=0.f; acck[j]=0.f; }
        for (int e=0;e<64;e++){
            float oq = orf_q[f*64+e];
            float ok = orf_k[f*64+e];
            const float* wq = Wq + e*64 + d0;
            const float* wk = Wk + e*64 + d0;
            #pragma unroll
            for (int j=0;j<8;j++){ accq[j] += oq*wq[j]; acck[j] += ok*wk[j]; }
        }
        #pragma unroll
        for (int j=0;j<8;j++){
            Mtq_l[f*72 + d0 + j] = (__bf16)(norm*accq[j]);
            Mtk_l[f*72 + d0 + j] = (__bf16)(norm*acck[j]);
        }
        if (tid < 64){
            float bacc = 0.f;
            for (int e=0;e<64;e++) bacc += orf_q[tid*64+e]*bq[e];
            cql[tid] = norm*bacc;
        } else if (tid < 128){
            const int f2 = tid - 64;
            float bacc = 0.f;
            for (int e=0;e<64;e++) bacc += orf_k[f2*64+e]*bk[e];
            ckl[f2] = norm*bacc;
        }
        #pragma unroll
        for (int i=0;i<8;i++){
            int idx = i*512 + tid;
            WvB_l[(idx >> 6)*72 + (idx & 63)] = (__bf16)Wv[idx];
        }
        // WfcB bf16 conversion, spread over blocks (consumed by kfc, 2 dispatches later)
        if (tid < 256){
            const int idx = bid*256 + tid;
            float4 v = ((const float4*)Wfc)[idx];
            bf16x4 o; o[0]=(__bf16)v.x; o[1]=(__bf16)v.y; o[2]=(__bf16)v.z; o[3]=(__bf16)v.w;
            *(bf16x4*)(WfcB + 4*idx) = o;
        }
    }
    __syncthreads();

    // ---- Phase 1: waves 0-3 q-proj, waves 4-7 k-proj ----
    {
        bf16x8 a0 = pack8(pA0, pA1);
        bf16x8 a1 = pack8(pB0, pB1);
        if (w < 4) {
            #pragma unroll
            for (int nt=0;nt<4;nt++){
                const int f = nt*16 + m;
                float cb = cql[f];
                f32x4 acc = {cb,cb,cb,cb};
                acc = MFMA16(a0, *(const bf16x8*)&Mtq_l[f*72 + qd*8], acc);
                acc = MFMA16(a1, *(const bf16x8*)&Mtq_l[f*72 + 32 + qd*8], acc);
                #pragma unroll
                for (int r=0;r<4;r++){
                    float v = acc[r];
                    v = (v>0.f)?v:0.f; v += 0.001f;
                    PHI_Q[((size_t)bh*SS + sw + qd*4 + r)*FF + f] = (__bf16)v;
                }
            }
        } else {
            #pragma unroll
            for (int nt=0;nt<4;nt++){
                const int f = nt*16 + m;
                float cb = ckl[f];
                f32x4 acc = {cb,cb,cb,cb};
                acc = MFMA16(a0, *(const bf16x8*)&Mtk_l[f*72 + qd*8], acc);
                acc = MFMA16(a1, *(const bf16x8*)&Mtk_l[f*72 + 32 + qd*8], acc);
                #pragma unroll
                for (int r=0;r<4;r++){
                    float v = acc[r];
                    v = (v>0.f)?v:0.f; v += 0.001f;
                    __bf16 h16 = (__bf16)v;
                    PHI_K[((size_t)bh*SS + sw + qd*4 + r)*FF + f] = h16;
                    kt[f*72 + ww*16 + qd*4 + r] = h16;
                }
            }
        }
    }
    __syncthreads();

    // ---- Phase 2: tid<256 store PHI_KT; waves 4-7 v-proj -> vt ----
    if (tid < 256) {
        const int f = tid >> 2, sg = tid & 3;
        bf16x8 v0 = *(bf16x8*)&kt[f*72 + sg*16];
        bf16x8 v1 = *(bf16x8*)&kt[f*72 + sg*16 + 8];
        bf16_t* dst = PHI_KT + ((size_t)bh*64 + f)*SS + s0 + sg*16;
        *(bf16x8*)dst = v0; *(bf16x8*)(dst+8) = v1;
    } else {
        bf16x8 a0 = pack8(vA0, vA1);
        bf16x8 a1 = pack8(vB0, vB1);
        #pragma unroll
        for (int nt=0;nt<4;nt++){
            const int e = nt*16 + m;
            float cb = bv[e];
            f32x4 acc = {cb,cb,cb,cb};
            acc = MFMA16(a0, *(const bf16x8*)&WvB_l[e*72 + qd*8], acc);
            acc = MFMA16(a1, *(const bf16x8*)&WvB_l[e*72 + 32 + qd*8], acc);
            #pragma unroll
            for (int r=0;r<4;r++)
                vt[e*72 + ww*16 + qd*4 + r] = (__bf16)acc[r];
        }
    }
    __syncthreads();

    // ---- Phase 3: chunk-sum MFMA (8 waves, ft x nt split) + VPT store + colsums ----
    {
        const int ft = ww, np = (w >> 2) * 2;
        bf16x8 a0 = *(bf16x8*)&kt[(ft*16+m)*72 + qd*8];
        bf16x8 a1 = *(bf16x8*)&kt[(ft*16+m)*72 + 32 + qd*8];
        #pragma unroll
        for (int j=0;j<2;j++){
            const int nt = np + j;
            f32x4 acc = {0.f,0.f,0.f,0.f};
            acc = MFMA16(a0, *(bf16x8*)&vt[(nt*16+m)*72 + qd*8], acc);
            acc = MFMA16(a1, *(bf16x8*)&vt[(nt*16+m)*72 + 32 + qd*8], acc);
            #pragma unroll
            for (int r=0;r<4;r++)
                dsT[(nt*16+m)*68 + ft*16 + qd*4 + r] = acc[r];
        }
    }
    if (tid < 256) {
        const int d = tid >> 2, sg = tid & 3;
        bf16x8 v0 = *(bf16x8*)&vt[d*72 + sg*16];
        bf16x8 v1 = *(bf16x8*)&vt[d*72 + sg*16 + 8];
        bf16_t* dst = VPT + ((size_t)bh*64 + d)*SS + s0 + sg*16;
        *(bf16x8*)dst = v0; *(bf16x8*)(dst+8) = v1;
    } else {
        const int t2 = tid - 256;
        const int f = t2 & 63, sg = t2 >> 6;
        bf16x8 x0 = *(bf16x8*)&kt[f*72 + sg*16];
        bf16x8 x1 = *(bf16x8*)&kt[f*72 + sg*16 + 8];
        float sm = 0.f;
        #pragma unroll
        for (int j=0;j<8;j++) sm += (float)x0[j] + (float)x1[j];
        part[sg*64 + f] = sm;
    }
    __syncthreads();

    // ---- Phase 4: CST (this chunk's raw sum) + KCS stores ----
    if (tid < 256) {
        const int d = tid >> 2, F = (tid & 3) * 16;
        float* dst = CST + ((size_t)bid*64 + d)*64 + F;
        #pragma unroll
        for (int j=0;j<4;j++)
            *(float4*)(dst + 4*j) = *(float4*)&dsT[d*68 + F + 4*j];
    } else if (tid < 320) {
        const int f = tid - 256;
        KCS[(size_t)bid*64 + f] = part[f] + part[64+f] + part[128+f] + part[192+f];
    }
}

// ---------------- kattn: per-chunk causal attention, inline exclusive prefix ----------------
// grid = 256 (bh*16+ch), 512 threads.
__global__ __launch_bounds__(512) void kattn(
    const bf16_t* __restrict__ PHI_Q, const bf16_t* __restrict__ PHI_K,
    const bf16_t* __restrict__ PHI_KT, const bf16_t* __restrict__ VPT,
    const float* __restrict__ CST, const float* __restrict__ KCS,
    bf16_t* __restrict__ O)
{
    __shared__ float kct[64*67];    // [f][s] kcum
    __shared__ bf16_t qnl[64*72];   // [s][f] qn
    __shared__ bf16_t sAl[64*72];   // [s][t] masked scores
    __shared__ bf16_t pT[64*72];    // [d][f] exclusive-prefix P (bf16)
    __shared__ float scanp[256];
    __shared__ float kcsp[64];
    const int tid = threadIdx.x;
    const int l = tid & 63;
    const int w = __builtin_amdgcn_readfirstlane(tid >> 6);  // 0..7
    const int rt = w & 3;            // row-tile
    const int np = (w >> 2) * 2;     // nt-pair start
    const int qd = l >> 4, m = l & 15;
    const int bid = blockIdx.x;
    const int bh = bid >> 4, ch = bid & 15;
    const int cs0 = ch*64;

    if (tid >= 256) {
        // ---- exclusive prefix P over earlier chunks (fp32, same order as old kprefix) ----
        const int t2 = tid - 256;
        const int base = t2 * 16;
        const int d = t2 >> 2, f0 = (t2 & 3) * 16;
        float acc[16];
        #pragma unroll
        for (int j=0;j<16;j++) acc[j]=0.f;
        for (int cc = 0; cc < ch; cc++) {
            const float4* p = (const float4*)(CST + ((size_t)(bh*NCH + cc))*4096 + base);
            #pragma unroll
            for (int j=0;j<4;j++){
                float4 t = p[j];
                acc[4*j]+=t.x; acc[4*j+1]+=t.y; acc[4*j+2]+=t.z; acc[4*j+3]+=t.w;
            }
        }
        bf16x8 o0, o1;
        #pragma unroll
        for (int j=0;j<8;j++){ o0[j]=(__bf16)acc[j]; o1[j]=(__bf16)acc[8+j]; }
        *(bf16x8*)&pT[d*72 + f0]     = o0;
        *(bf16x8*)&pT[d*72 + f0 + 8] = o1;
    } else {
        // ---- S1: phi_k^T chunk -> kct fp32; tid<64 also: KCS exclusive prefix ----
        const int f = tid >> 2, sg = tid & 3;
        const bf16_t* kp = PHI_KT + ((size_t)bh*64 + f)*SS + cs0 + sg*16;
        bf16x8 x0 = *(const bf16x8*)kp;
        bf16x8 x1 = *(const bf16x8*)(kp+8);
        #pragma unroll
        for (int j=0;j<8;j++){
            kct[f*67 + sg*16 + j]     = (float)x0[j];
            kct[f*67 + sg*16 + 8 + j] = (float)x1[j];
        }
        if (tid < 64) {
            float r = 0.f;
            for (int cc = 0; cc < ch; cc++) r += KCS[((size_t)(bh*NCH + cc))*64 + tid];
            kcsp[tid] = r;
        }
    }
    __syncthreads();

    // S2: inclusive scan along s per f, seeded with exclusive kcsp
    const int f2 = tid >> 2, sg2 = tid & 3;
    float v16[16];
    if (tid < 256) {
        #pragma unroll
        for (int j=0;j<16;j++) v16[j] = kct[f2*67 + sg2*16 + j];
        #pragma unroll
        for (int j=1;j<16;j++) v16[j] += v16[j-1];
        scanp[f2*4 + sg2] = v16[15];
    }
    __syncthreads();
    if (tid < 256) {
        float offs = kcsp[f2];
        if (sg2 > 0) offs += scanp[f2*4 + 0];
        if (sg2 > 1) offs += scanp[f2*4 + 1];
        if (sg2 > 2) offs += scanp[f2*4 + 2];
        #pragma unroll
        for (int j=0;j<16;j++) kct[f2*67 + sg2*16 + j] = offs + v16[j];
    }
    __syncthreads();

    // S3: qn = phi_q / kcum -> qnl bf16 [s][f]
    if (tid < 256) {
        const int sr = tid >> 2, F = (tid & 3) * 16;
        const bf16_t* qp = PHI_Q + ((size_t)bh*SS + cs0 + sr)*FF + F;
        bf16x8 x0 = *(const bf16x8*)qp;
        bf16x8 x1 = *(const bf16x8*)(qp+8);
        bf16x8 o0, o1;
        #pragma unroll
        for (int j=0;j<8;j++){
            o0[j] = (__bf16)((float)x0[j] / kct[(F+j)*67 + sr]);
            o1[j] = (__bf16)((float)x1[j] / kct[(F+8+j)*67 + sr]);
        }
        *(bf16x8*)&qnl[sr*72 + F]     = o0;
        *(bf16x8*)&qnl[sr*72 + F + 8] = o1;
    }
    __syncthreads();

    bf16x8 qa0 = *(bf16x8*)&qnl[(rt*16+m)*72 + qd*8];
    bf16x8 qa1 = *(bf16x8*)&qnl[(rt*16+m)*72 + 32 + qd*8];

    // S4: S = tril(qn @ phi_k^T); wave handles t-tiles {np, np+1}
    #pragma unroll
    for (int j=0;j<2;j++){
        const int nt = np + j;
        const bf16_t* kb = PHI_K + ((size_t)bh*SS + cs0 + nt*16 + m)*FF;
        f32x4 acc = {0.f,0.f,0.f,0.f};
        acc = MFMA16(qa0, *(const bf16x8*)(kb + qd*8), acc);
        acc = MFMA16(qa1, *(const bf16x8*)(kb + 32 + qd*8), acc);
        const int t_loc = nt*16 + m;
        #pragma unroll
        for (int r=0;r<4;r++){
            const int s_loc = rt*16 + qd*4 + r;
            float v = (t_loc <= s_loc) ? acc[r] : 0.f;
            sAl[s_loc*72 + t_loc] = (__bf16)v;
        }
    }
    __syncthreads();

    bf16x8 sa0 = *(bf16x8*)&sAl[(rt*16+m)*72 + qd*8];
    bf16x8 sa1 = *(bf16x8*)&sAl[(rt*16+m)*72 + 32 + qd*8];

    // S5: O = S@v' + qn@P; wave handles d-tiles {np, np+1}
    #pragma unroll
    for (int j=0;j<2;j++){
        const int nt = np + j;
        const int d = nt*16 + m;
        const bf16_t* vb = VPT + ((size_t)bh*64 + d)*SS + cs0;
        f32x4 acc = {0.f,0.f,0.f,0.f};
        acc = MFMA16(sa0, *(const bf16x8*)(vb + qd*8), acc);
        acc = MFMA16(sa1, *(const bf16x8*)(vb + 32 + qd*8), acc);
        acc = MFMA16(qa0, *(const bf16x8*)&pT[d*72 + qd*8], acc);
        acc = MFMA16(qa1, *(const bf16x8*)&pT[d*72 + 32 + qd*8], acc);
        #pragma unroll
        for (int r=0;r<4;r++)
            O[((size_t)bh*SS + cs0 + rt*16 + qd*4 + r)*DD + d] = (__bf16)acc[r];
    }
}

// ---------------- kfc: out = O @ Wfc^T + bfc (512 thr, 8-wave split) ----------------
// grid = 32 rowtiles * 8 coltiles = 256 blocks, 512 threads.
__global__ __launch_bounds__(512) void kfc(
    const bf16_t* __restrict__ O, const bf16_t* __restrict__ WfcB,
    const float* __restrict__ bfc, float* __restrict__ out)
{
    const int tid = threadIdx.x;
    const int l = tid & 63;
    const int w = __builtin_amdgcn_readfirstlane(tid >> 6);  // 0..7
    const int rw = w & 3, cpair = (w >> 2) * 2;
    const int qd = l >> 4, m = l & 15;
    const int bid = blockIdx.x;
    const int rb = bid >> 3, cb = bid & 7;
    const int r0 = rb*64 + rw*16;

    f32x4 acc[2];
    #pragma unroll
    for (int j=0;j<2;j++){
        float bb = bfc[cb*64 + (cpair+j)*16 + m];
        acc[j][0]=bb; acc[j][1]=bb; acc[j][2]=bb; acc[j][3]=bb;
    }
    const int row = r0 + m;
    const int b = row >> 10, s = row & 1023;
    #pragma unroll 4
    for (int c=0;c<16;c++){
        const int h = c >> 1;
        const int doff = (c & 1)*32 + qd*8;
        bf16x8 a = *(const bf16x8*)(O + ((size_t)((b*HH + h)*SS + s))*DD + doff);
        #pragma unroll
        for (int j=0;j<2;j++){
            bf16x8 bfr = *(const bf16x8*)(WfcB + (size_t)(cb*64 + (cpair+j)*16 + m)*DM + c*32 + qd*8);
            acc[j] = MFMA16(a, bfr, acc[j]);
        }
    }
    #pragma unroll
    for (int j=0;j<2;j++){
        #pragma unroll
        for (int r=0;r<4;r++){
            const int rr = r0 + qd*4 + r;
            out[(size_t)rr*DM + cb*64 + (cpair+j)*16 + m] = acc[j][r];
        }
    }
}

extern "C" void kernel_launch(void* const* d_in, const int* in_sizes, int n_in,
                              void* d_out, int out_size, void* d_ws, size_t ws_size,
                              hipStream_t stream) {
    const float* q_in  = (const float*)d_in[0];
    const float* k_in  = (const float*)d_in[1];
    const float* v_in  = (const float*)d_in[2];
    const float* Wq    = (const float*)d_in[3];
    const float* bq    = (const float*)d_in[4];
    const float* Wk    = (const float*)d_in[5];
    const float* bk    = (const float*)d_in[6];
    const float* Wv    = (const float*)d_in[7];
    const float* bv    = (const float*)d_in[8];
    const float* orf_q = (const float*)d_in[9];
    const float* orf_k = (const float*)d_in[10];
    const float* Wfc   = (const float*)d_in[11];
    const float* bfc   = (const float*)d_in[12];

    float* CST   = (float*)d_ws;                 // 1048576 fp32 (raw per-chunk sums)
    float* KCS   = CST + 1048576;                // 16384 fp32 (raw per-chunk colsums)
    bf16_t* PHI_Q  = (bf16_t*)(KCS + 16384);     // 1M bf16 each
    bf16_t* PHI_K  = PHI_Q + 1048576;
    bf16_t* PHI_KT = PHI_K + 1048576;
    bf16_t* VPT    = PHI_KT + 1048576;
    bf16_t* O      = VPT + 1048576;
    bf16_t* WfcB   = O + 1048576;                // 262144

    kproj<<<256, 512, 0, stream>>>(q_in, k_in, v_in, Wq, bq, Wk, bk, Wv, bv,
                                   orf_q, orf_k, Wfc,
                                   PHI_Q, PHI_K, PHI_KT, VPT, CST, KCS, WfcB);
    kattn<<<256, 512, 0, stream>>>(PHI_Q, PHI_K, PHI_KT, VPT, CST, KCS, O);
    kfc<<<256, 512, 0, stream>>>(O, WfcB, bfc, (float*)d_out);
}